// Round 8
// baseline (240.134 us; speedup 1.0000x reference)
//
#include <hip/hip_runtime.h>
#include <math.h>

// CTC loss, T=1024 B=64 V=256 L=256 (S=513).
// One WAVE per batch element, zero barriers, zero LDS ops in the main loop.
// R7 post-mortem: per-step 345 cyc was DS-pipe bound — shfl_up (ds_bpermute
// ~100+ cyc) on the serial path, 5 random-index LDS gathers (1.15M conflict
// cycles) in the in-order DS queue, and a 6-deep dependent shfl_xor butterfly
// every 16 steps. This version:
//  - cross-lane alpha neighbor via DPP wave_shr:1 (VALU pipe, ~4 cyc),
//  - renorm max via DPP row_shr/row_bcast reduction + readlane (VALU),
//  - e-values gathered DIRECTLY from global memory (L3-warm: the lse waves
//    stream the whole tensor ahead of the recursion): 5 scalar loads per row
//    (blank + 4 label indices), issued 8 rows ahead into named register slots
//    (vmcnt slack ~7 steps ~ 700 cyc). No ds_write/ds_read round-trip at all.
//  - LINEAR-domain recursion on RAW logits (log-softmax denominator deferred:
//    per-(t,b) additive constant factors out; cumlse computed by lse waves).
//  - Renorm every 16 steps (growth <= ~2^118 < 2^127), exact accounting via
//    log2acc -= log2f(inv).
//  - loss_b = cumlse[b] - ( ln(a[end]+a[end-1]) + ln2*log2acc )

constexpr int V = 256;
constexpr float LN2_F = 0.6931471805599453f;

// lane l gets lane l-1's value; lane 0 gets 0. VALU-pipe (v_mov_b32 dpp).
__device__ __forceinline__ float dpp_sr1(float x) {
    return __int_as_float(__builtin_amdgcn_update_dpp(
        0, __float_as_int(x), 0x138 /*WAVE_SHR1*/, 0xf, 0xf, true));
}

// wave-wide max, result uniform (via readlane 63). Classic gfx9 DPP ladder.
__device__ __forceinline__ float wave_max_uniform(float v) {
#define DPPMAX(CTRL)                                                     \
    v = fmaxf(v, __int_as_float(__builtin_amdgcn_update_dpp(             \
            0, __float_as_int(v), CTRL, 0xf, 0xf, true)))
    DPPMAX(0x111);  // row_shr:1
    DPPMAX(0x112);  // row_shr:2
    DPPMAX(0x114);  // row_shr:4
    DPPMAX(0x118);  // row_shr:8
    DPPMAX(0x142);  // row_bcast:15
    DPPMAX(0x143);  // row_bcast:31
#undef DPPMAX
    return __int_as_float(__builtin_amdgcn_readlane(__float_as_int(v), 63));
}

#define MACS(EB, E1, E3, E5, E7) do {                                  \
    const float _c7m = dpp_sr1(cur7);     /* alpha[s-1] from prev lane */\
    curT = (curT + cur7) * (EB);                                       \
    cur7 = fmaf(sk7, cur5, cur7 + cur6) * (E7);                        \
    cur6 = (cur6 + cur5) * (EB);                                       \
    cur5 = fmaf(sk5, cur3, cur5 + cur4) * (E5);                        \
    cur4 = (cur4 + cur3) * (EB);                                       \
    cur3 = fmaf(sk3, cur1, cur3 + cur2) * (E3);                        \
    cur2 = (cur2 + cur1) * (EB);                                       \
    cur1 = fmaf(sk1, _c7m, cur1 + cur0) * (E1);                        \
    cur0 = (cur0 + _c7m) * (EB);                                       \
  } while (0)

// issue 5 raw-value gathers for row RR into slot SL (named regs, vmcnt queue)
#define GLOAD(SL, RR) do {                                             \
    int _r = (RR); if (_r > Tbm1) _r = Tbm1;                           \
    const float* _rp = lg + (size_t)_r * rs;                           \
    g##SL##b = _rp[0];  g##SL##p = _rp[ix]; g##SL##q = _rp[iy];        \
    g##SL##r = _rp[iz]; g##SL##s = _rp[iw];                            \
  } while (0)

// one step: MACS on exp'd set EC; wait+exp raw slot SLN (row TT+1) into EN;
// refill slot SLN with row TT+9.
#define STEP(TT, EC, EN, SLN) do {                                     \
    MACS(EC##b, EC##p, EC##q, EC##r, EC##s);                           \
    EN##b = __expf(g##SLN##b); EN##p = __expf(g##SLN##p);              \
    EN##q = __expf(g##SLN##q); EN##r = __expf(g##SLN##r);              \
    EN##s = __expf(g##SLN##s);                                         \
    GLOAD(SLN, (TT) + 9);                                              \
  } while (0)

#define RENORM do {                                                    \
    curT *= mkT; cur0 *= mk0; cur1 *= mk1; cur2 *= mk2; cur3 *= mk3;   \
    cur4 *= mk4; cur5 *= mk5; cur6 *= mk6; cur7 *= mk7;                \
    float _m = fmaxf(curT, cur0); _m = fmaxf(_m, cur1);                \
    _m = fmaxf(_m, cur2); _m = fmaxf(_m, cur3); _m = fmaxf(_m, cur4);  \
    _m = fmaxf(_m, cur5); _m = fmaxf(_m, cur6); _m = fmaxf(_m, cur7);  \
    const float _M = wave_max_uniform(fmaxf(_m, 1e-30f));              \
    const float _inv = 1.f / _M;                                       \
    log2acc -= log2f(_inv);                                            \
    curT *= _inv; cur0 *= _inv; cur1 *= _inv; cur2 *= _inv;            \
    cur3 *= _inv; cur4 *= _inv; cur5 *= _inv; cur6 *= _inv;            \
    cur7 *= _inv;                                                      \
  } while (0)

__global__ __launch_bounds__(64) void ctc_main(
    const int*   __restrict__ labels,      // [B, L]
    const float* __restrict__ logits,      // [T, B, V]
    const int*   __restrict__ label_len,   // [B]
    const int*   __restrict__ logit_len,   // [B]
    float*       __restrict__ partial,     // [nLse] per-wave lse sums
    float*       __restrict__ lnterm,      // [B]
    int T, int B, int L)
{
    const int l = threadIdx.x;             // lane == thread

    if ((int)blockIdx.x < B) {
        // =============== recursion: one wave, one batch element ==============
        const int b = blockIdx.x;
        __shared__ float afin[514];        // final alpha for readout (epilogue)

        const int Tb = logit_len[b];
        const int Lb = label_len[b];
        const int Sb = 2 * Lb + 1;
        const int Tbm1 = Tb - 1;

        const float* lg = logits + (size_t)b * V;
        const size_t rs = (size_t)B * V;

        const int4 lb4 = ((const int4*)(labels + (size_t)b * L))[l];
        const int ix = lb4.x, iy = lb4.y, iz = lb4.z, iw = lb4.w;
        const int prevw = __shfl_up(iw, 1);              // labels[4l-1]
        const float sk1 = (l > 0 && ix != prevw) ? 1.f : 0.f;
        const float sk3 = (iy != ix) ? 1.f : 0.f;
        const float sk5 = (iz != iy) ? 1.f : 0.f;
        const float sk7 = (iw != iz) ? 1.f : 0.f;

        const float mk0 = (8 * l + 0 < Sb) ? 1.f : 0.f;
        const float mk1 = (8 * l + 1 < Sb) ? 1.f : 0.f;
        const float mk2 = (8 * l + 2 < Sb) ? 1.f : 0.f;
        const float mk3 = (8 * l + 3 < Sb) ? 1.f : 0.f;
        const float mk4 = (8 * l + 4 < Sb) ? 1.f : 0.f;
        const float mk5 = (8 * l + 5 < Sb) ? 1.f : 0.f;
        const float mk6 = (8 * l + 6 < Sb) ? 1.f : 0.f;
        const float mk7 = (8 * l + 7 < Sb) ? 1.f : 0.f;
        const float mkT = (Sb > 512 && l == 63) ? 1.f : 0.f;

        // t=0 init: states 0,1 only
        float cur0 = 0.f, cur1 = 0.f, cur2 = 0.f, cur3 = 0.f;
        float cur4 = 0.f, cur5 = 0.f, cur6 = 0.f, cur7 = 0.f, curT = 0.f;
        if (l == 0) {
            cur0 = __expf(lg[0]);
            cur1 = __expf(lg[ix]) * mk1;
        }

        // 8 gather slots (5 named regs each) + 2 exp'd sets (double buffer)
        float g0b = 0, g0p = 0, g0q = 0, g0r = 0, g0s = 0;
        float g1b = 0, g1p = 0, g1q = 0, g1r = 0, g1s = 0;
        float g2b = 0, g2p = 0, g2q = 0, g2r = 0, g2s = 0;
        float g3b = 0, g3p = 0, g3q = 0, g3r = 0, g3s = 0;
        float g4b = 0, g4p = 0, g4q = 0, g4r = 0, g4s = 0;
        float g5b = 0, g5p = 0, g5q = 0, g5r = 0, g5s = 0;
        float g6b = 0, g6p = 0, g6q = 0, g6r = 0, g6s = 0;
        float g7b = 0, g7p = 0, g7q = 0, g7r = 0, g7s = 0;
        float eAb = 0, eAp = 0, eAq = 0, eAr = 0, eAs = 0;
        float eBb = 0, eBp = 0, eBq = 0, eBr = 0, eBs = 0;

        float log2acc = 0.f;
        int base = 1;
        if (Tb >= 16) {
            // prologue: issue rows 1..8 into slots 1..7,0 (in t order)
            GLOAD(1, 1); GLOAD(2, 2); GLOAD(3, 3); GLOAD(4, 4);
            GLOAD(5, 5); GLOAD(6, 6); GLOAD(7, 7); GLOAD(0, 8);
            // exp row 1 (slot 1) -> eA (consumed at t=1); refill slot 1 = row 9
            eAb = __expf(g1b); eAp = __expf(g1p); eAq = __expf(g1q);
            eAr = __expf(g1r); eAs = __expf(g1s);
            GLOAD(1, 9);
            // first window: t = 1..15
            STEP(1,  eA, eB, 2);  STEP(2,  eB, eA, 3);  STEP(3,  eA, eB, 4);
            STEP(4,  eB, eA, 5);  STEP(5,  eA, eB, 6);  STEP(6,  eB, eA, 7);
            STEP(7,  eA, eB, 0);  STEP(8,  eB, eA, 1);  STEP(9,  eA, eB, 2);
            STEP(10, eB, eA, 3);  STEP(11, eA, eB, 4);  STEP(12, eB, eA, 5);
            STEP(13, eA, eB, 6);  STEP(14, eB, eA, 7);  STEP(15, eA, eB, 0);
            RENORM;
            // main windows: base ≡ 0 (mod 16)
            for (base = 16; base + 16 <= Tb; base += 16) {
                STEP(base + 0,  eB, eA, 1);  STEP(base + 1,  eA, eB, 2);
                STEP(base + 2,  eB, eA, 3);  STEP(base + 3,  eA, eB, 4);
                STEP(base + 4,  eB, eA, 5);  STEP(base + 5,  eA, eB, 6);
                STEP(base + 6,  eB, eA, 7);  STEP(base + 7,  eA, eB, 0);
                STEP(base + 8,  eB, eA, 1);  STEP(base + 9,  eA, eB, 2);
                STEP(base + 10, eB, eA, 3);  STEP(base + 11, eA, eB, 4);
                STEP(base + 12, eB, eA, 5);  STEP(base + 13, eA, eB, 6);
                STEP(base + 14, eB, eA, 7);  STEP(base + 15, eA, eB, 0);
                RENORM;
            }
        }
        // scalar tail (t = base..Tb-1): <=15 unrenormed steps cannot overflow
        for (int t = base; t < Tb; ++t) {
            const float* rowp = lg + (size_t)t * rs;
            const float eb = __expf(rowp[0]);
            const float e1 = __expf(rowp[ix]), e3 = __expf(rowp[iy]);
            const float e5 = __expf(rowp[iz]), e7 = __expf(rowp[iw]);
            MACS(eb, e1, e3, e5, e7);
        }

        // readout: ln(a[end] + a[end-1]) + ln2*log2acc
        afin[8 * l + 0] = cur0; afin[8 * l + 1] = cur1;
        afin[8 * l + 2] = cur2; afin[8 * l + 3] = cur3;
        afin[8 * l + 4] = cur4; afin[8 * l + 5] = cur5;
        afin[8 * l + 6] = cur6; afin[8 * l + 7] = cur7;
        if (l == 63) afin[512] = curT;
        const int end = 2 * Lb;
        const int em1 = (end > 0) ? end - 1 : 0;
        float ssum = afin[end] + afin[em1];     // same-wave DS, in-order
        ssum = fmaxf(ssum, 1e-37f);             // inf-protection only
        if (l == 0) lnterm[b] = logf(ssum) + LN2_F * log2acc;
    } else {
        // ====== lse waves: partial[w] = sum of lse over rows r ≡ w (mod nW) ==
        const int w  = blockIdx.x - B;          // 0..nW-1
        const int nW = gridDim.x - B;
        const int rows = T * B;
        const int bb = w % B;                   // constant per wave
        const int Tbb = logit_len[bb];
        float acc = 0.f;
        int r = w;
        if (r < rows) {
            float4 nxt = ((const float4*)(logits + (size_t)r * V))[l];
            while (true) {
                const int rn = r + nW;
                const bool more = rn < rows;
                const float4 x = nxt;
                if (more) nxt = ((const float4*)(logits + (size_t)rn * V))[l];
                float m = fmaxf(fmaxf(x.x, x.y), fmaxf(x.z, x.w));
                #pragma unroll
                for (int o = 32; o >= 1; o >>= 1)
                    m = fmaxf(m, __shfl_xor(m, o, 64));
                float ss = __expf(x.x - m) + __expf(x.y - m) +
                           __expf(x.z - m) + __expf(x.w - m);
                #pragma unroll
                for (int o = 32; o >= 1; o >>= 1) ss += __shfl_xor(ss, o, 64);
                const int t = r / B;
                if (t < Tbb) acc += m + logf(ss);
                if (!more) break;
                r = rn;
            }
        }
        if (l == 0) partial[w] = acc;
    }
}

__global__ __launch_bounds__(64) void ctc_final(
    const float* __restrict__ partial,     // [nW]
    const float* __restrict__ lnterm,      // [B]
    float* __restrict__ out, int B, int nW)
{
    const int b = threadIdx.x;
    float v = 0.f;
    if (b < B) {
        float c = 0.f;
        for (int k = b; k < nW; k += B) c += partial[k];
        v = c - lnterm[b];
    }
    #pragma unroll
    for (int o = 32; o >= 1; o >>= 1) v += __shfl_xor(v, o, 64);
    if (threadIdx.x == 0) out[0] = v / (float)B;
}

extern "C" void kernel_launch(void* const* d_in, const int* in_sizes, int n_in,
                              void* d_out, int out_size, void* d_ws, size_t ws_size,
                              hipStream_t stream) {
    const int*   labels    = (const int*)d_in[0];
    const float* logits    = (const float*)d_in[1];
    const int*   label_len = (const int*)d_in[2];
    const int*   logit_len = (const int*)d_in[3];

    const int B = in_sizes[2];                 // 64
    const int L = in_sizes[0] / B;             // 256
    const int T = in_sizes[1] / (B * V);       // 1024

    const int nLse = 1024;                     // 64 rows per lse wave
    float* partial = (float*)d_ws;             // [nLse]
    float* lnterm  = partial + nLse;           // [B]

    ctc_main<<<B + nLse, 64, 0, stream>>>(labels, logits, label_len, logit_len,
                                          partial, lnterm, T, B, L);
    ctc_final<<<1, 64, 0, stream>>>(partial, lnterm, (float*)d_out, B, nLse);
}

// Round 9
// 234.565 us; speedup vs baseline: 1.0237x; 1.0237x over previous
//
#include <hip/hip_runtime.h>
#include <math.h>

// CTC loss, T=1024 B=64 V=256 L=256 (S=513).
// R8 post-mortem: 5 scattered global gathers/step are TA-throughput-bound
// (~16 transactions each), unhideable by depth on a single wave. This round
// moves the gather OFF the serial path entirely:
//   ctc_prep (parallel, BW-bound): per (t,b) row computes exact softmax
//     p = exp(x-m)/sum (the log-softmax denominator is folded in HERE, so no
//     cumlse anywhere), gathers p[labels[b][0..255]] via LDS, packs bf16-RNE
//     into pv[b][t][256]; blank prob (vocab 0) kept fp32 in pblk[b][t].
//   ctc_rec (serial, one wave per b): per step ONE coalesced 8B load (lane's
//     4 label-probs) + ONE broadcast fp32 load (blank), 16-deep named register
//     slots, DPP cross-lane, renorm every 8 steps. ~30 instr/step, no DS ops,
//     no scattered VMEM.
//   loss_b = -( ln(a[end]+a[end-1]) + ln2*log2acc )   (alpha now in p-domain)
// Fallback: if ws_size < ~34 MB, run the proven R8 monolithic kernel.

constexpr int V = 256;
constexpr float LN2_F = 0.6931471805599453f;

// lane l gets lane l-1's value; lane 0 gets 0 (VALU-pipe DPP).
__device__ __forceinline__ float dpp_sr1(float x) {
    return __int_as_float(__builtin_amdgcn_update_dpp(
        0, __float_as_int(x), 0x138 /*WAVE_SHR1*/, 0xf, 0xf, true));
}

// wave-wide max, uniform result (DPP ladder + readlane 63).
__device__ __forceinline__ float wave_max_uniform(float v) {
#define DPPMAX(CTRL, RM)                                                 \
    v = fmaxf(v, __int_as_float(__builtin_amdgcn_update_dpp(             \
            0, __float_as_int(v), CTRL, RM, 0xf, true)))
    DPPMAX(0x111, 0xf);  // row_shr:1
    DPPMAX(0x112, 0xf);  // row_shr:2
    DPPMAX(0x114, 0xf);  // row_shr:4
    DPPMAX(0x118, 0xf);  // row_shr:8
    DPPMAX(0x142, 0xa);  // row_bcast:15
    DPPMAX(0x143, 0xc);  // row_bcast:31
#undef DPPMAX
    return __int_as_float(__builtin_amdgcn_readlane(__float_as_int(v), 63));
}

__device__ __forceinline__ unsigned bf16rne(float f) {   // round-nearest-even
    unsigned u = __float_as_uint(f);
    u += 0x7FFFu + ((u >> 16) & 1u);
    return u >> 16;
}

#define MACS(EB, E1, E3, E5, E7) do {                                  \
    const float _c7m = dpp_sr1(cur7);     /* alpha[s-1] from prev lane */\
    curT = (curT + cur7) * (EB);                                       \
    cur7 = fmaf(sk7, cur5, cur7 + cur6) * (E7);                        \
    cur6 = (cur6 + cur5) * (EB);                                       \
    cur5 = fmaf(sk5, cur3, cur5 + cur4) * (E5);                        \
    cur4 = (cur4 + cur3) * (EB);                                       \
    cur3 = fmaf(sk3, cur1, cur3 + cur2) * (E3);                        \
    cur2 = (cur2 + cur1) * (EB);                                       \
    cur1 = fmaf(sk1, _c7m, cur1 + cur0) * (E1);                        \
    cur0 = (cur0 + _c7m) * (EB);                                       \
  } while (0)

#define RENORM do {                                                    \
    curT *= mkT; cur0 *= mk0; cur1 *= mk1; cur2 *= mk2; cur3 *= mk3;   \
    cur4 *= mk4; cur5 *= mk5; cur6 *= mk6; cur7 *= mk7;                \
    float _m = fmaxf(curT, cur0); _m = fmaxf(_m, cur1);                \
    _m = fmaxf(_m, cur2); _m = fmaxf(_m, cur3); _m = fmaxf(_m, cur4);  \
    _m = fmaxf(_m, cur5); _m = fmaxf(_m, cur6); _m = fmaxf(_m, cur7);  \
    const float _M = wave_max_uniform(fmaxf(_m, 1e-30f));              \
    const float _inv = 1.f / _M;                                       \
    log2acc -= log2f(_inv);                                            \
    curT *= _inv; cur0 *= _inv; cur1 *= _inv; cur2 *= _inv;            \
    cur3 *= _inv; cur4 *= _inv; cur5 *= _inv; cur6 *= _inv;            \
    cur7 *= _inv;                                                      \
  } while (0)

// ===================== primary path: prep + rec + final =====================

__global__ __launch_bounds__(256) void ctc_prep(
    const int*   __restrict__ labels,   // [B, L]
    const float* __restrict__ logits,   // [T, B, V]
    unsigned short* __restrict__ pv,    // [B, T, 256] bf16 gathered label-probs
    float*       __restrict__ pblk,     // [B, T] fp32 blank prob
    int T, int B, int L)
{
    const int l  = threadIdx.x & 63;
    const int wv = threadIdx.x >> 6;              // wave in block (0..3)
    __shared__ float lrow[4][V];                  // wave-private p row

    const int gw   = blockIdx.x * 4 + wv;         // global wave id
    const int totW = gridDim.x * 4;
    const int b    = gw % B;
    const int t0   = gw / B;
    const int nT   = totW / B;

    const int4 lb4 = ((const int4*)(labels + (size_t)b * L))[l];
    float* ld = lrow[wv];

    for (int t = t0; t < T; t += nT) {
        const float4 x =
            ((const float4*)(logits + ((size_t)t * B + b) * V))[l];
        float m = fmaxf(fmaxf(x.x, x.y), fmaxf(x.z, x.w));
        #pragma unroll
        for (int o = 32; o >= 1; o >>= 1) m = fmaxf(m, __shfl_xor(m, o, 64));
        const float e0 = __expf(x.x - m), e1 = __expf(x.y - m);
        const float e2 = __expf(x.z - m), e3 = __expf(x.w - m);
        float s = e0 + e1 + e2 + e3;
        #pragma unroll
        for (int o = 32; o >= 1; o >>= 1) s += __shfl_xor(s, o, 64);
        const float inv = 1.f / s;                // exact softmax (m cancels)
        float4 p; p.x = e0*inv; p.y = e1*inv; p.z = e2*inv; p.w = e3*inv;
        ((float4*)ld)[l] = p;
        // same-wave DS is in-order; runtime-index reads can't pass the write
        const float y0 = ld[lb4.x], y1 = ld[lb4.y];
        const float y2 = ld[lb4.z], y3 = ld[lb4.w];
        uint2 pk;
        pk.x = bf16rne(y0) | (bf16rne(y1) << 16);
        pk.y = bf16rne(y2) | (bf16rne(y3) << 16);
        ((uint2*)(pv + ((size_t)b * T + t) * V))[l] = pk;
        if (l == 0) pblk[(size_t)b * T + t] = p.x;  // vocab 0 = lane0 elem0
    }
}

// fill slot SL with row RR (clamped)
#define PFILL(SL, RR) do {                                             \
    int _r = (RR); if (_r > Tbm1) _r = Tbm1;                           \
    pk##SL = *(const uint2*)(pvb + (size_t)_r * V + 4 * l);            \
    bk##SL = pbb[_r];                                                  \
  } while (0)

// one step: unpack+MACS slot SL (row TT), refill with row TT+16
#define PSTEP(TT, SL) do {                                             \
    const float _e1 = __uint_as_float(pk##SL.x << 16);                 \
    const float _e3 = __uint_as_float(pk##SL.x & 0xFFFF0000u);         \
    const float _e5 = __uint_as_float(pk##SL.y << 16);                 \
    const float _e7 = __uint_as_float(pk##SL.y & 0xFFFF0000u);         \
    const float _eb = bk##SL;                                          \
    MACS(_eb, _e1, _e3, _e5, _e7);                                     \
    PFILL(SL, (TT) + 16);                                              \
  } while (0)

__global__ __launch_bounds__(64) void ctc_rec(
    const int*   __restrict__ labels,        // [B, L] (skip masks only)
    const unsigned short* __restrict__ pv,   // [B, T, 256]
    const float* __restrict__ pblk,          // [B, T]
    const int*   __restrict__ label_len,     // [B]
    const int*   __restrict__ logit_len,     // [B]
    float*       __restrict__ lnterm,        // [B] log-likelihood
    int T, int B, int L)
{
    const int l = threadIdx.x;
    const int b = blockIdx.x;
    __shared__ float afin[514];

    const int Tb = logit_len[b];
    const int Lb = label_len[b];
    const int Sb = 2 * Lb + 1;
    const int Tbm1 = Tb - 1;

    const unsigned short* pvb = pv + (size_t)b * T * V;
    const float*          pbb = pblk + (size_t)b * T;

    const int4 lb4 = ((const int4*)(labels + (size_t)b * L))[l];
    const int prevw = __shfl_up(lb4.w, 1);            // labels[4l-1]
    const float sk1 = (l > 0 && lb4.x != prevw) ? 1.f : 0.f;
    const float sk3 = (lb4.y != lb4.x) ? 1.f : 0.f;
    const float sk5 = (lb4.z != lb4.y) ? 1.f : 0.f;
    const float sk7 = (lb4.w != lb4.z) ? 1.f : 0.f;

    const float mk0 = (8 * l + 0 < Sb) ? 1.f : 0.f;
    const float mk1 = (8 * l + 1 < Sb) ? 1.f : 0.f;
    const float mk2 = (8 * l + 2 < Sb) ? 1.f : 0.f;
    const float mk3 = (8 * l + 3 < Sb) ? 1.f : 0.f;
    const float mk4 = (8 * l + 4 < Sb) ? 1.f : 0.f;
    const float mk5 = (8 * l + 5 < Sb) ? 1.f : 0.f;
    const float mk6 = (8 * l + 6 < Sb) ? 1.f : 0.f;
    const float mk7 = (8 * l + 7 < Sb) ? 1.f : 0.f;
    const float mkT = (Sb > 512 && l == 63) ? 1.f : 0.f;

    // t=0 init: alpha0 = p(blank), alpha1 = p(label0)
    float cur0 = 0.f, cur1 = 0.f, cur2 = 0.f, cur3 = 0.f;
    float cur4 = 0.f, cur5 = 0.f, cur6 = 0.f, cur7 = 0.f, curT = 0.f;
    if (l == 0) {
        cur0 = pbb[0];
        cur1 = __uint_as_float((unsigned)pvb[0] << 16) * mk1;
    }

    // 16 named slots: uint2 packed bf16x4 + fp32 blank (3 VGPRs each)
    uint2 pk0, pk1, pk2, pk3, pk4, pk5, pk6, pk7;
    uint2 pk8, pk9, pk10, pk11, pk12, pk13, pk14, pk15;
    float bk0, bk1, bk2, bk3, bk4, bk5, bk6, bk7;
    float bk8, bk9, bk10, bk11, bk12, bk13, bk14, bk15;

    float log2acc = 0.f;
    int base = 1;
    if (Tb >= 16) {
        // prologue: rows 1..16 -> slots (row & 15)
        PFILL(1, 1);   PFILL(2, 2);   PFILL(3, 3);   PFILL(4, 4);
        PFILL(5, 5);   PFILL(6, 6);   PFILL(7, 7);   PFILL(8, 8);
        PFILL(9, 9);   PFILL(10, 10); PFILL(11, 11); PFILL(12, 12);
        PFILL(13, 13); PFILL(14, 14); PFILL(15, 15); PFILL(0, 16);
        // first window t = 1..15
        PSTEP(1, 1);   PSTEP(2, 2);   PSTEP(3, 3);   PSTEP(4, 4);
        PSTEP(5, 5);   PSTEP(6, 6);   PSTEP(7, 7);   PSTEP(8, 8);
        RENORM;
        PSTEP(9, 9);   PSTEP(10, 10); PSTEP(11, 11); PSTEP(12, 12);
        PSTEP(13, 13); PSTEP(14, 14); PSTEP(15, 15);
        RENORM;
        for (base = 16; base + 16 <= Tb; base += 16) {
            PSTEP(base + 0, 0);   PSTEP(base + 1, 1);
            PSTEP(base + 2, 2);   PSTEP(base + 3, 3);
            PSTEP(base + 4, 4);   PSTEP(base + 5, 5);
            PSTEP(base + 6, 6);   PSTEP(base + 7, 7);
            RENORM;
            PSTEP(base + 8, 8);   PSTEP(base + 9, 9);
            PSTEP(base + 10, 10); PSTEP(base + 11, 11);
            PSTEP(base + 12, 12); PSTEP(base + 13, 13);
            PSTEP(base + 14, 14); PSTEP(base + 15, 15);
            RENORM;
        }
    }
    // scalar tail: <=15 un-renormed steps (decay bounded; last renorm close)
    for (int t = base; t < Tb; ++t) {
        const unsigned short* rw = pvb + (size_t)t * V;
        const float e1 = __uint_as_float((unsigned)rw[4 * l + 0] << 16);
        const float e3 = __uint_as_float((unsigned)rw[4 * l + 1] << 16);
        const float e5 = __uint_as_float((unsigned)rw[4 * l + 2] << 16);
        const float e7 = __uint_as_float((unsigned)rw[4 * l + 3] << 16);
        const float eb = pbb[t];
        MACS(eb, e1, e3, e5, e7);
    }

    // readout: ll = ln(a[end] + a[end-1]) + ln2*log2acc   (denominator baked)
    afin[8 * l + 0] = cur0; afin[8 * l + 1] = cur1;
    afin[8 * l + 2] = cur2; afin[8 * l + 3] = cur3;
    afin[8 * l + 4] = cur4; afin[8 * l + 5] = cur5;
    afin[8 * l + 6] = cur6; afin[8 * l + 7] = cur7;
    if (l == 63) afin[512] = curT;
    const int end = 2 * Lb;
    const int em1 = (end > 0) ? end - 1 : 0;
    float ssum = afin[end] + afin[em1];          // same-wave DS, in-order
    ssum = fmaxf(ssum, 1e-37f);                  // inf-protection only
    if (l == 0) lnterm[b] = logf(ssum) + LN2_F * log2acc;
}

__global__ __launch_bounds__(64) void ctc_final_p(
    const float* __restrict__ lnterm, float* __restrict__ out, int B)
{
    float v = (threadIdx.x < B) ? lnterm[threadIdx.x] : 0.f;
    #pragma unroll
    for (int o = 32; o >= 1; o >>= 1) v += __shfl_xor(v, o, 64);
    if (threadIdx.x == 0) out[0] = -v / (float)B;
}

// ======================= fallback path (R8, proven) =========================

#define GLOAD(SL, RR) do {                                             \
    int _r = (RR); if (_r > Tbm1) _r = Tbm1;                           \
    const float* _rp = lg + (size_t)_r * rs;                           \
    g##SL##b = _rp[0];  g##SL##p = _rp[ix]; g##SL##q = _rp[iy];        \
    g##SL##r = _rp[iz]; g##SL##s = _rp[iw];                            \
  } while (0)

#define GSTEP(TT, EC, EN, SLN) do {                                    \
    MACS(EC##b, EC##p, EC##q, EC##r, EC##s);                           \
    EN##b = __expf(g##SLN##b); EN##p = __expf(g##SLN##p);              \
    EN##q = __expf(g##SLN##q); EN##r = __expf(g##SLN##r);              \
    EN##s = __expf(g##SLN##s);                                         \
    GLOAD(SLN, (TT) + 9);                                              \
  } while (0)

__global__ __launch_bounds__(64) void ctc_main_g(
    const int* __restrict__ labels, const float* __restrict__ logits,
    const int* __restrict__ label_len, const int* __restrict__ logit_len,
    float* __restrict__ partial, float* __restrict__ lnterm,
    int T, int B, int L)
{
    const int l = threadIdx.x;
    if ((int)blockIdx.x < B) {
        const int b = blockIdx.x;
        __shared__ float afin[514];
        const int Tb = logit_len[b];
        const int Lb = label_len[b];
        const int Sb = 2 * Lb + 1;
        const int Tbm1 = Tb - 1;
        const float* lg = logits + (size_t)b * V;
        const size_t rs = (size_t)B * V;
        const int4 lb4 = ((const int4*)(labels + (size_t)b * L))[l];
        const int ix = lb4.x, iy = lb4.y, iz = lb4.z, iw = lb4.w;
        const int prevw = __shfl_up(iw, 1);
        const float sk1 = (l > 0 && ix != prevw) ? 1.f : 0.f;
        const float sk3 = (iy != ix) ? 1.f : 0.f;
        const float sk5 = (iz != iy) ? 1.f : 0.f;
        const float sk7 = (iw != iz) ? 1.f : 0.f;
        const float mk0 = (8*l+0 < Sb) ? 1.f : 0.f;
        const float mk1 = (8*l+1 < Sb) ? 1.f : 0.f;
        const float mk2 = (8*l+2 < Sb) ? 1.f : 0.f;
        const float mk3 = (8*l+3 < Sb) ? 1.f : 0.f;
        const float mk4 = (8*l+4 < Sb) ? 1.f : 0.f;
        const float mk5 = (8*l+5 < Sb) ? 1.f : 0.f;
        const float mk6 = (8*l+6 < Sb) ? 1.f : 0.f;
        const float mk7 = (8*l+7 < Sb) ? 1.f : 0.f;
        const float mkT = (Sb > 512 && l == 63) ? 1.f : 0.f;
        float cur0 = 0.f, cur1 = 0.f, cur2 = 0.f, cur3 = 0.f;
        float cur4 = 0.f, cur5 = 0.f, cur6 = 0.f, cur7 = 0.f, curT = 0.f;
        if (l == 0) { cur0 = __expf(lg[0]); cur1 = __expf(lg[ix]) * mk1; }
        float g0b=0,g0p=0,g0q=0,g0r=0,g0s=0, g1b=0,g1p=0,g1q=0,g1r=0,g1s=0;
        float g2b=0,g2p=0,g2q=0,g2r=0,g2s=0, g3b=0,g3p=0,g3q=0,g3r=0,g3s=0;
        float g4b=0,g4p=0,g4q=0,g4r=0,g4s=0, g5b=0,g5p=0,g5q=0,g5r=0,g5s=0;
        float g6b=0,g6p=0,g6q=0,g6r=0,g6s=0, g7b=0,g7p=0,g7q=0,g7r=0,g7s=0;
        float eAb=0,eAp=0,eAq=0,eAr=0,eAs=0, eBb=0,eBp=0,eBq=0,eBr=0,eBs=0;
        float log2acc = 0.f;
        int base = 1;
        if (Tb >= 16) {
            GLOAD(1,1); GLOAD(2,2); GLOAD(3,3); GLOAD(4,4);
            GLOAD(5,5); GLOAD(6,6); GLOAD(7,7); GLOAD(0,8);
            eAb=__expf(g1b); eAp=__expf(g1p); eAq=__expf(g1q);
            eAr=__expf(g1r); eAs=__expf(g1s);
            GLOAD(1,9);
            GSTEP(1,eA,eB,2);  GSTEP(2,eB,eA,3);  GSTEP(3,eA,eB,4);
            GSTEP(4,eB,eA,5);  GSTEP(5,eA,eB,6);  GSTEP(6,eB,eA,7);
            GSTEP(7,eA,eB,0);  GSTEP(8,eB,eA,1);  GSTEP(9,eA,eB,2);
            GSTEP(10,eB,eA,3); GSTEP(11,eA,eB,4); GSTEP(12,eB,eA,5);
            GSTEP(13,eA,eB,6); GSTEP(14,eB,eA,7); GSTEP(15,eA,eB,0);
            RENORM;
            for (base = 16; base + 16 <= Tb; base += 16) {
                GSTEP(base+0,eB,eA,1);  GSTEP(base+1,eA,eB,2);
                GSTEP(base+2,eB,eA,3);  GSTEP(base+3,eA,eB,4);
                GSTEP(base+4,eB,eA,5);  GSTEP(base+5,eA,eB,6);
                GSTEP(base+6,eB,eA,7);  GSTEP(base+7,eA,eB,0);
                GSTEP(base+8,eB,eA,1);  GSTEP(base+9,eA,eB,2);
                GSTEP(base+10,eB,eA,3); GSTEP(base+11,eA,eB,4);
                GSTEP(base+12,eB,eA,5); GSTEP(base+13,eA,eB,6);
                GSTEP(base+14,eB,eA,7); GSTEP(base+15,eA,eB,0);
                RENORM;
            }
        }
        for (int t = base; t < Tb; ++t) {
            const float* rowp = lg + (size_t)t * rs;
            const float eb = __expf(rowp[0]);
            const float e1 = __expf(rowp[ix]), e3 = __expf(rowp[iy]);
            const float e5 = __expf(rowp[iz]), e7 = __expf(rowp[iw]);
            MACS(eb, e1, e3, e5, e7);
        }
        afin[8*l+0]=cur0; afin[8*l+1]=cur1; afin[8*l+2]=cur2; afin[8*l+3]=cur3;
        afin[8*l+4]=cur4; afin[8*l+5]=cur5; afin[8*l+6]=cur6; afin[8*l+7]=cur7;
        if (l == 63) afin[512] = curT;
        const int end = 2 * Lb;
        const int em1 = (end > 0) ? end - 1 : 0;
        float ssum = afin[end] + afin[em1];
        ssum = fmaxf(ssum, 1e-37f);
        if (l == 0) lnterm[b] = logf(ssum) + LN2_F * log2acc;
    } else {
        const int w  = blockIdx.x - B;
        const int nW = gridDim.x - B;
        const int rows = T * B;
        const int bb = w % B;
        const int Tbb = logit_len[bb];
        float acc = 0.f;
        int r = w;
        if (r < rows) {
            float4 nxt = ((const float4*)(logits + (size_t)r * V))[l];
            while (true) {
                const int rn = r + nW;
                const bool more = rn < rows;
                const float4 x = nxt;
                if (more) nxt = ((const float4*)(logits + (size_t)rn * V))[l];
                float m = fmaxf(fmaxf(x.x, x.y), fmaxf(x.z, x.w));
                #pragma unroll
                for (int o = 32; o >= 1; o >>= 1)
                    m = fmaxf(m, __shfl_xor(m, o, 64));
                float ss = __expf(x.x-m)+__expf(x.y-m)+__expf(x.z-m)+__expf(x.w-m);
                #pragma unroll
                for (int o = 32; o >= 1; o >>= 1) ss += __shfl_xor(ss, o, 64);
                const int t = r / B;
                if (t < Tbb) acc += m + logf(ss);
                if (!more) break;
                r = rn;
            }
        }
        if (l == 0) partial[w] = acc;
    }
}

__global__ __launch_bounds__(64) void ctc_final_g(
    const float* __restrict__ partial, const float* __restrict__ lnterm,
    float* __restrict__ out, int B, int nW)
{
    const int b = threadIdx.x;
    float v = 0.f;
    if (b < B) {
        float c = 0.f;
        for (int k = b; k < nW; k += B) c += partial[k];
        v = c - lnterm[b];
    }
    #pragma unroll
    for (int o = 32; o >= 1; o >>= 1) v += __shfl_xor(v, o, 64);
    if (threadIdx.x == 0) out[0] = v / (float)B;
}

extern "C" void kernel_launch(void* const* d_in, const int* in_sizes, int n_in,
                              void* d_out, int out_size, void* d_ws, size_t ws_size,
                              hipStream_t stream) {
    const int*   labels    = (const int*)d_in[0];
    const float* logits    = (const float*)d_in[1];
    const int*   label_len = (const int*)d_in[2];
    const int*   logit_len = (const int*)d_in[3];

    const int B = in_sizes[2];                 // 64
    const int L = in_sizes[0] / B;             // 256
    const int T = in_sizes[1] / (B * V);       // 1024

    const size_t pvBytes = (size_t)B * T * V * sizeof(unsigned short); // 33.6MB
    const size_t pbBytes = (size_t)B * T * sizeof(float);              // 256KB
    const size_t need    = pvBytes + pbBytes + (size_t)B * sizeof(float);

    if (ws_size >= need) {
        unsigned short* pv = (unsigned short*)d_ws;
        float* pblk   = (float*)((char*)d_ws + pvBytes);
        float* lnterm = (float*)((char*)d_ws + pvBytes + pbBytes);
        ctc_prep<<<512, 256, 0, stream>>>(labels, logits, pv, pblk, T, B, L);
        ctc_rec<<<B, 64, 0, stream>>>(labels, pv, pblk, label_len, logit_len,
                                      lnterm, T, B, L);
        ctc_final_p<<<1, 64, 0, stream>>>(lnterm, (float*)d_out, B);
    } else {
        const int nLse = 1024;
        float* partial = (float*)d_ws;
        float* lnterm  = partial + nLse;
        ctc_main_g<<<B + nLse, 64, 0, stream>>>(labels, logits, label_len,
                                                logit_len, partial, lnterm,
                                                T, B, L);
        ctc_final_g<<<1, 64, 0, stream>>>(partial, lnterm, (float*)d_out,
                                          B, nLse);
    }
}